// Round 1
// baseline (83.317 us; speedup 1.0000x reference)
//
#include <hip/hip_runtime.h>

// LearnableHadamard: reference pads x[...,768] to 1024, applies the
// interleaved-butterfly unnormalized FWHT twice, truncates to 768, adds
// residual. The interleaved FWHT is T = P·H (P = bit-reversal, H = natural
// Hadamard). P commutes with H and P^2 = I, so T^2 = H^2 = N·I = 1024·I.
// Therefore out = 1024*x + x = 1025*x, exactly. params' values are unused
// (only shape[0]=2 matters). => single memory-bound elementwise scale.

__global__ void LearnableHadamard_scale1025(const float4* __restrict__ in,
                                            float4* __restrict__ out,
                                            int n4) {
    int idx = blockIdx.x * blockDim.x + threadIdx.x;
    int stride = gridDim.x * blockDim.x;
    for (int i = idx; i < n4; i += stride) {
        float4 v = in[i];
        v.x *= 1025.0f;
        v.y *= 1025.0f;
        v.z *= 1025.0f;
        v.w *= 1025.0f;
        out[i] = v;
    }
}

extern "C" void kernel_launch(void* const* d_in, const int* in_sizes, int n_in,
                              void* d_out, int out_size, void* d_ws, size_t ws_size,
                              hipStream_t stream) {
    const float* x = (const float*)d_in[0];   // (64, 1024, 768) fp32
    // d_in[1] = params (2,1024) — values unused by the reference op.
    float* out = (float*)d_out;               // same shape as x

    int n = in_sizes[0];                      // 64*1024*768 = 50331648, %4 == 0
    int n4 = n >> 2;                          // 12,582,912 float4 elements

    const int block = 256;
    int grid = (n4 + block - 1) / block;
    if (grid > 2048) grid = 2048;             // grid-stride the rest (G11)

    LearnableHadamard_scale1025<<<grid, block, 0, stream>>>(
        (const float4*)x, (float4*)out, n4);
}

// Round 2
// 75.772 us; speedup vs baseline: 1.0996x; 1.0996x over previous
//
#include <hip/hip_runtime.h>

// LearnableHadamard: reference pads x[...,768] to 1024, applies the
// interleaved-butterfly unnormalized FWHT twice, truncates to 768, adds
// residual. The interleaved FWHT is T = P·H (P = bit-reversal permutation,
// H = natural-order Hadamard). P commutes with H and P^2 = I, so
// T^2 = H^2 = N·I = 1024·I. Therefore out = 1024*x + x = 1025*x exactly.
// params' values are unused (only shape[0]=2 matters).
// => single memory-bound elementwise scale; target = float4-copy ceiling
// (~6.3 TB/s, ~64 us for 402 MB).
//
// Round 1 -> 2: 83 us @ 4.8 TB/s with 1-load-1-store grid-stride loop.
// Fix: unroll x4 with 4 independent loads issued before the 4 stores
// (more in-flight VMEM per wave), exact-cover grid (n4 = 1024 * 12288,
// evenly divisible -> no tail), 48 blocks/CU.

__global__ void __launch_bounds__(256)
LearnableHadamard_scale1025(const float4* __restrict__ in,
                            float4* __restrict__ out) {
    // Each block moves 4 contiguous chunks of 256 float4s.
    int base = blockIdx.x * (256 * 4) + threadIdx.x;

    float4 v0 = in[base + 0 * 256];
    float4 v1 = in[base + 1 * 256];
    float4 v2 = in[base + 2 * 256];
    float4 v3 = in[base + 3 * 256];

    v0.x *= 1025.0f; v0.y *= 1025.0f; v0.z *= 1025.0f; v0.w *= 1025.0f;
    v1.x *= 1025.0f; v1.y *= 1025.0f; v1.z *= 1025.0f; v1.w *= 1025.0f;
    v2.x *= 1025.0f; v2.y *= 1025.0f; v2.z *= 1025.0f; v2.w *= 1025.0f;
    v3.x *= 1025.0f; v3.y *= 1025.0f; v3.z *= 1025.0f; v3.w *= 1025.0f;

    out[base + 0 * 256] = v0;
    out[base + 1 * 256] = v1;
    out[base + 2 * 256] = v2;
    out[base + 3 * 256] = v3;
}

// Tail-safe fallback for any leftover elements (not used at this shape,
// kept for correctness robustness).
__global__ void LearnableHadamard_scale1025_tail(const float* __restrict__ in,
                                                 float* __restrict__ out,
                                                 int start, int n) {
    int i = start + blockIdx.x * blockDim.x + threadIdx.x;
    if (i < n) out[i] = in[i] * 1025.0f;
}

extern "C" void kernel_launch(void* const* d_in, const int* in_sizes, int n_in,
                              void* d_out, int out_size, void* d_ws, size_t ws_size,
                              hipStream_t stream) {
    const float* x = (const float*)d_in[0];   // (64, 1024, 768) fp32
    float* out = (float*)d_out;

    int n = in_sizes[0];                      // 50,331,648
    int n4 = n >> 2;                          // 12,582,912 float4
    const int per_block = 256 * 4;            // float4s per block
    int grid = n4 / per_block;                // 12288, exact cover

    LearnableHadamard_scale1025<<<grid, 256, 0, stream>>>(
        (const float4*)x, (float4*)out);

    int covered4 = grid * per_block;
    int covered = covered4 << 2;
    if (covered < n) {
        int rem = n - covered;
        LearnableHadamard_scale1025_tail<<<(rem + 255) / 256, 256, 0, stream>>>(
            x, out, covered, n);
    }
}

// Round 4
// 72.352 us; speedup vs baseline: 1.1515x; 1.0473x over previous
//
#include <hip/hip_runtime.h>

// LearnableHadamard: reference pads x[...,768] to 1024, applies the
// interleaved-butterfly unnormalized FWHT twice, truncates to 768, adds
// residual. The interleaved FWHT is T = P·H (P = bit-reversal permutation,
// H = natural-order Hadamard). P commutes with H and P^2 = I, so
// T^2 = H^2 = N·I = 1024·I. Therefore out = 1024*x + x = 1025*x exactly.
// params' values are unused (only shape[0]=2 matters).
// => single memory-bound elementwise scale; target = float4-copy ceiling
// (~6.3 TB/s, ~64 us for 402 MB).
//
// R1: 83.3 us @ 4.8 TB/s (1 load + 1 store grid-stride).
// R2: 75.8 us @ 5.3 TB/s (x4 unroll, exact-cover grid).
// R3: compile fail — __builtin_nontemporal_* rejects HIP_vector_type.
// R4: same plan with native ext_vector_type(4): x8 unroll (8 independent
//     nt-loads in flight per lane) + non-temporal stores (384 MB stream
//     > 256 MB L3 -> cache allocation is pure thrash; nt bypasses it).

typedef float f32x4 __attribute__((ext_vector_type(4)));

__global__ void __launch_bounds__(256)
LearnableHadamard_scale1025(const f32x4* __restrict__ in,
                            f32x4* __restrict__ out) {
    // Each block moves 8 contiguous chunks of 256 float4s (32 KB).
    int base = blockIdx.x * (256 * 8) + threadIdx.x;

    f32x4 v0 = __builtin_nontemporal_load(&in[base + 0 * 256]);
    f32x4 v1 = __builtin_nontemporal_load(&in[base + 1 * 256]);
    f32x4 v2 = __builtin_nontemporal_load(&in[base + 2 * 256]);
    f32x4 v3 = __builtin_nontemporal_load(&in[base + 3 * 256]);
    f32x4 v4 = __builtin_nontemporal_load(&in[base + 4 * 256]);
    f32x4 v5 = __builtin_nontemporal_load(&in[base + 5 * 256]);
    f32x4 v6 = __builtin_nontemporal_load(&in[base + 6 * 256]);
    f32x4 v7 = __builtin_nontemporal_load(&in[base + 7 * 256]);

    v0 *= 1025.0f;
    v1 *= 1025.0f;
    v2 *= 1025.0f;
    v3 *= 1025.0f;
    v4 *= 1025.0f;
    v5 *= 1025.0f;
    v6 *= 1025.0f;
    v7 *= 1025.0f;

    __builtin_nontemporal_store(v0, &out[base + 0 * 256]);
    __builtin_nontemporal_store(v1, &out[base + 1 * 256]);
    __builtin_nontemporal_store(v2, &out[base + 2 * 256]);
    __builtin_nontemporal_store(v3, &out[base + 3 * 256]);
    __builtin_nontemporal_store(v4, &out[base + 4 * 256]);
    __builtin_nontemporal_store(v5, &out[base + 5 * 256]);
    __builtin_nontemporal_store(v6, &out[base + 6 * 256]);
    __builtin_nontemporal_store(v7, &out[base + 7 * 256]);
}

// Tail-safe fallback for any leftover elements (not used at this shape).
__global__ void LearnableHadamard_scale1025_tail(const float* __restrict__ in,
                                                 float* __restrict__ out,
                                                 int start, int n) {
    int i = start + blockIdx.x * blockDim.x + threadIdx.x;
    if (i < n) out[i] = in[i] * 1025.0f;
}

extern "C" void kernel_launch(void* const* d_in, const int* in_sizes, int n_in,
                              void* d_out, int out_size, void* d_ws, size_t ws_size,
                              hipStream_t stream) {
    const float* x = (const float*)d_in[0];   // (64, 1024, 768) fp32
    float* out = (float*)d_out;

    int n = in_sizes[0];                      // 50,331,648
    int n4 = n >> 2;                          // 12,582,912 float4
    const int per_block = 256 * 8;            // float4s per block
    int grid = n4 / per_block;                // 6144, exact cover

    LearnableHadamard_scale1025<<<grid, 256, 0, stream>>>(
        (const f32x4*)x, (f32x4*)out);

    int covered = (grid * per_block) << 2;
    if (covered < n) {
        int rem = n - covered;
        LearnableHadamard_scale1025_tail<<<(rem + 255) / 256, 256, 0, stream>>>(
            x, out, covered, n);
    }
}